// Round 11
// baseline (47.927 us; speedup 1.0000x reference)
//
#include <hip/hip_runtime.h>
#include <float.h>

// Problem constants (match reference)
#define BSX 2.0f
#define BSY 2.0f
#define NBX 512
#define NBY 512
#define MAX_SPAN 4
#define TINY 1.17549435e-38f   // np.finfo(float32).tiny

// ---- Tiled path parameters ----
#define TSB 5                  // log2(tile size in bins): 32x32 bins = 64x64 units
#define TS  32
#define NTT 16                 // tiles per axis (512/32)
#define NTILES 256
#define BTH 256
#define NPT 4                  // nets per thread
#define NPB (BTH * NPT)        // nets per block = 1024
#define CSTRIDE 32             // cursor padding: 32 u32 = 128 B = one line per counter
#define G 8                    // cursor/list shards per tile
#define SEG 768                // entries per (tile,shard) segment (mean ~537, +10 sigma)
#define ATH 256                // accum threads (3*ATH == SEG)

// fixed-point accumulation scale (validated r2/r5: per-bin sums ~150 << 2^9 headroom)
#define FP_SCALE 4194304.0f    // 2^22
#define FP_INV   (1.0f / 4194304.0f)

typedef unsigned int u32;
typedef unsigned long long ull;

// Entry (16B, self-contained), tile-local quantized bbox + premultiplied weights:
//   x: x0q(1/1024 unit) | dxq(1/16384)<<16
//   y: y0q | dyq<<16
//   z: bits(w/(dy+tiny))   [h weight]
//   w: bits(w/(dx+tiny))   [v weight]

// ============================ tiled path ============================

__global__ __launch_bounds__(256) void init_cursors(u32* __restrict__ cursor)
{
    int i = blockIdx.x * 256 + threadIdx.x;
    if (i < NTILES * G) cursor[(u32)i * CSTRIDE] = 0u;
}

// Minimal-phase binning: count -> reserve -> direct-scatter emit.
// LDS = 2 KB -> 8 blocks/CU residency; entire grid co-resident, phases of
// different blocks overlap (latency hiding across blocks, not within).
__global__ __launch_bounds__(BTH) void bin_nets(
    const float* __restrict__ pin_pos,
    const float* __restrict__ net_weights,
    const int*   __restrict__ netpin_start,
    const int*   __restrict__ flat_netpin,
    u32*         __restrict__ cursor,     // [NTILES*G] padded by CSTRIDE
    uint4*       __restrict__ list,       // [NTILES*G][SEG]
    int num_nets, int n_total)
{
    __shared__ u32 s_cnt[NTILES];     // counts -> segment bases
    __shared__ u32 s_fill[NTILES];    // emit fill offsets

    int tid = threadIdx.x;
    int g = blockIdx.x & (G - 1);     // shard for this block
    s_cnt[tid] = 0u; s_fill[tid] = 0u;   // BTH == NTILES
    __syncthreads();

    int bs = blockIdx.x * NPB;

    // ---- phase-split loads: max memory-level parallelism ----
    int sA[NPT], eA[NPT];
    #pragma unroll
    for (int k = 0; k < NPT; ++k) {
        sA[k] = 0; eA[k] = 0;
        int i = bs + k * BTH + tid;
        if (i < num_nets) { sA[k] = netpin_start[i]; eA[k] = netpin_start[i + 1]; }
    }
    int4 fA[NPT];
    #pragma unroll
    for (int k = 0; k < NPT; ++k) {
        fA[k] = make_int4(-1, -1, -1, -1);
        if (eA[k] - sA[k] == 4 && (sA[k] & 3) == 0)
            fA[k] = *(const int4*)(flat_netpin + sA[k]);
    }
    bool idA[NPT];
    float4 xvA[NPT], yvA[NPT];
    #pragma unroll
    for (int k = 0; k < NPT; ++k) {
        int s = sA[k];
        idA[k] = (fA[k].x == s && fA[k].y == s + 1 && fA[k].z == s + 2 && fA[k].w == s + 3);
        if (idA[k]) {
            xvA[k] = *(const float4*)(pin_pos + s);
            yvA[k] = *(const float4*)(pin_pos + s + n_total);
        }
    }
    float wgt[NPT];
    #pragma unroll
    for (int k = 0; k < NPT; ++k) {
        int i = bs + k * BTH + tid;
        wgt[k] = (i < num_nets) ? net_weights[i] : 0.0f;
    }

    // ---- pass 1: bbox + per-tile counting ----
    float fx0[NPT], fx1[NPT], fy0[NPT], fy1[NPT], fwh[NPT], fwv[NPT];
    u32 trng[NPT];   // packed txl | txh<<8 | tyl<<16 | tyh<<24 ; 0x01 => invalid

    #pragma unroll
    for (int k = 0; k < NPT; ++k) {
        trng[k] = 0x00000001u;
        fx0[k] = 0.f; fx1[k] = 0.f; fy0[k] = 0.f; fy1[k] = 0.f;
        fwh[k] = 0.f; fwv[k] = 0.f;
        int i = bs + k * BTH + tid;
        if (i < num_nets) {
            bool have = false;
            float xmin, xmax, ymin, ymax;
            if (idA[k]) {
                xmin = fminf(fminf(xvA[k].x, xvA[k].y), fminf(xvA[k].z, xvA[k].w));
                xmax = fmaxf(fmaxf(xvA[k].x, xvA[k].y), fmaxf(xvA[k].z, xvA[k].w));
                ymin = fminf(fminf(yvA[k].x, yvA[k].y), fminf(yvA[k].z, yvA[k].w));
                ymax = fmaxf(fmaxf(yvA[k].x, yvA[k].y), fmaxf(yvA[k].z, yvA[k].w));
                have = true;
            } else if (eA[k] > sA[k]) {
                xmin = FLT_MAX; xmax = -FLT_MAX; ymin = FLT_MAX; ymax = -FLT_MAX;
                for (int p = sA[k]; p < eA[k]; ++p) {
                    int idx = flat_netpin[p];
                    float x = pin_pos[idx], y = pin_pos[idx + n_total];
                    xmin = fminf(xmin, x); xmax = fmaxf(xmax, x);
                    ymin = fminf(ymin, y); ymax = fmaxf(ymax, y);
                }
                have = true;
            }
            if (have) {
                fx0[k] = xmin; fx1[k] = xmax; fy0[k] = ymin; fy1[k] = ymax;
                fwh[k] = wgt[k] / (ymax - ymin + TINY);
                fwv[k] = wgt[k] / (xmax - xmin + TINY);
                int ixl = min(max((int)(xmin * 0.5f), 0), NBX - 1);
                int ixh = min(min((int)(xmax * 0.5f) + 1, NBX), ixl + MAX_SPAN);
                int iyl = min(max((int)(ymin * 0.5f), 0), NBY - 1);
                int iyh = min(min((int)(ymax * 0.5f) + 1, NBY), iyl + MAX_SPAN);
                int txl = ixl >> TSB, txh = (ixh - 1) >> TSB;
                int tyl = iyl >> TSB, tyh = (iyh - 1) >> TSB;
                trng[k] = (u32)txl | ((u32)txh << 8) | ((u32)tyl << 16) | ((u32)tyh << 24);
                for (int tx = txl; tx <= txh; ++tx)
                    for (int ty = tyl; ty <= tyh; ++ty)
                        atomicAdd(&s_cnt[tx * NTT + ty], 1u);
            }
        }
    }
    __syncthreads();

    // ---- sharded global reserve: one atomic per touched tile ----
    {
        u32 c = s_cnt[tid];              // BTH == NTILES
        u32 gbase = 0;
        if (c) gbase = atomicAdd(&cursor[((u32)tid * G + (u32)g) * CSTRIDE], c);
        s_cnt[tid] = gbase;              // s_cnt now holds base within (tile,g) segment
    }
    __syncthreads();

    // ---- pass 2: direct-scatter emit (block's slots are contiguous) ----
    #pragma unroll
    for (int k = 0; k < NPT; ++k) {
        u32 tr = trng[k];
        int txl = (int)(tr & 0xFFu), txh = (int)((tr >> 8) & 0xFFu);
        int tyl = (int)((tr >> 16) & 0xFFu), tyh = (int)(tr >> 24);
        for (int tx = txl; tx <= txh; ++tx) {
            float tox = (float)(tx << TSB) * BSX;
            float rx0 = fminf(fmaxf(fx0[k] - tox, 0.0f), 64.0f);
            float rx1 = fminf(fmaxf(fx1[k] - tox, 0.0f), 64.0f);
            u32 x0q = min((u32)(rx0 * 1024.0f + 0.5f), 65535u);
            u32 dxq = min((u32)((rx1 - rx0) * 16384.0f + 0.5f), 65535u);
            for (int ty = tyl; ty <= tyh; ++ty) {
                float toy = (float)(ty << TSB) * BSY;
                float ry0 = fminf(fmaxf(fy0[k] - toy, 0.0f), 64.0f);
                float ry1 = fminf(fmaxf(fy1[k] - toy, 0.0f), 64.0f);
                u32 y0q = min((u32)(ry0 * 1024.0f + 0.5f), 65535u);
                u32 dyq = min((u32)((ry1 - ry0) * 16384.0f + 0.5f), 65535u);
                int t = tx * NTT + ty;
                uint4 pk;
                pk.x = x0q | (dxq << 16);
                pk.y = y0q | (dyq << 16);
                pk.z = __float_as_uint(fwh[k]);
                pk.w = __float_as_uint(fwv[k]);
                u32 slot = atomicAdd(&s_fill[t], 1u);
                u32 pos = s_cnt[t] + slot;
                if (pos < (u32)SEG)
                    list[(size_t)((u32)t * G + (u32)g) * SEG + pos] = pk;
            }
        }
    }
}

// One block per (tile, shard): accumulate segment into LDS u64 tile, dump partial.
__global__ __launch_bounds__(ATH) void accum_part(
    const uint4* __restrict__ list,
    const u32*   __restrict__ cursor,    // padded
    ull*         __restrict__ partial)   // [NTILES*G][TS*TS]
{
    __shared__ ull shv[TS * TS];   // packed fixed-point: hi32 = h, lo32 = v

    int b = blockIdx.x;            // b = t*G + g
    int tid = threadIdx.x;
    #pragma unroll
    for (int j = 0; j < 4; ++j) shv[tid + j * ATH] = 0ull;
    __syncthreads();

    u32 n = min(cursor[(u32)b * CSTRIDE], (u32)SEG);
    const uint4* lst = list + (size_t)b * SEG;

    // static 3-deep prefetch: SEG == 3*ATH
    uint4 t0, t1, t2;
    u32 e0 = tid, e1 = tid + ATH, e2 = tid + 2 * ATH;
    if (e0 < n) t0 = lst[e0];
    if (e1 < n) t1 = lst[e1];
    if (e2 < n) t2 = lst[e2];

    #define PROCESS(EE, PP)                                                     \
    if ((EE) < n) {                                                             \
        uint4 p = (PP);                                                         \
        float x0 = (float)(p.x & 0xFFFFu) * (1.0f / 1024.0f);                   \
        float x1 = x0 + (float)(p.x >> 16) * (1.0f / 16384.0f);                 \
        float y0 = (float)(p.y & 0xFFFFu) * (1.0f / 1024.0f);                   \
        float y1 = y0 + (float)(p.y >> 16) * (1.0f / 16384.0f);                 \
        float wh = __uint_as_float(p.z);                                        \
        float wv = __uint_as_float(p.w);                                        \
        int rxl = min((int)(x0 * 0.5f), TS - 1);                                \
        int rxh = min((int)(x1 * 0.5f) + 1, TS);                                \
        int ryl = min((int)(y0 * 0.5f), TS - 1);                                \
        int ryh = min((int)(y1 * 0.5f) + 1, TS);                                \
        for (int bx = rxl; bx < rxh; ++bx) {                                    \
            float bl = (float)bx * BSX;                                         \
            float ox = fmaxf(fminf(x1, bl + BSX) - fmaxf(x0, bl), 0.0f);        \
            float oxh = ox * wh * FP_SCALE, oxv = ox * wv * FP_SCALE;           \
            int rowbase = bx * TS;                                              \
            for (int by = ryl; by < ryh; ++by) {                                \
                float bb = (float)by * BSY;                                     \
                float oy = fmaxf(fminf(y1, bb + BSY) - fmaxf(y0, bb), 0.0f);    \
                u32 hq = (u32)(oxh * oy + 0.5f);                                \
                u32 vq = (u32)(oxv * oy + 0.5f);                                \
                ull pk = ((ull)hq << 32) | (ull)vq;                             \
                atomicAdd(&shv[rowbase + by], pk);                              \
            }                                                                   \
        }                                                                       \
    }

    PROCESS(e0, t0)  PROCESS(e1, t1)  PROCESS(e2, t2)
    #undef PROCESS

    __syncthreads();

    ull* dst = partial + (size_t)b * (TS * TS);
    #pragma unroll
    for (int j = 0; j < 4; ++j) dst[tid + j * ATH] = shv[tid + j * ATH];
}

__global__ __launch_bounds__(256) void merge_final(
    const ull* __restrict__ partial,
    float*     __restrict__ out)
{
    int k = blockIdx.x * 256 + threadIdx.x;     // k < NBX*NBY
    int t = k >> 10;            // tile index (tx*16+ty)
    int q = k & 1023;           // bin-in-tile (bx*32+by)

    const ull* p = partial + (size_t)t * G * (TS * TS) + q;
    // field-wise sum: per-bin field totals < 2^32, so u64 adds never carry across
    ull s = 0ull;
    #pragma unroll
    for (int g = 0; g < G; ++g) s += p[(size_t)g * (TS * TS)];

    float h = (float)(u32)(s >> 32);
    float v = (float)(u32)(s & 0xFFFFFFFFull);

    int tx = t >> 4, ty = t & 15;
    int bx = q >> 5, by = q & 31;
    out[(size_t)(tx * TS + bx) * NBY + (ty * TS + by)] =
        fmaxf(h, v) * (FP_INV * (1.0f / 6.0f));
}

// ======================= fallback path (round-2) =======================

__global__ void rudy_accum_fb(const float* __restrict__ pin_pos,
                              const float* __restrict__ net_weights,
                              const int*   __restrict__ netpin_start,
                              const int*   __restrict__ flat_netpin,
                              ull*         __restrict__ hv,
                              int num_nets, int n_total)
{
    int i = blockIdx.x * blockDim.x + threadIdx.x;
    if (i >= num_nets) return;
    int s = netpin_start[i], e = netpin_start[i + 1];
    if (e <= s) return;
    float xmin = FLT_MAX, xmax = -FLT_MAX, ymin = FLT_MAX, ymax = -FLT_MAX;
    for (int p = s; p < e; ++p) {
        int idx = flat_netpin[p];
        float x = pin_pos[idx], y = pin_pos[idx + n_total];
        xmin = fminf(xmin, x); xmax = fmaxf(xmax, x);
        ymin = fminf(ymin, y); ymax = fmaxf(ymax, y);
    }
    int ixl = min(max((int)(xmin * 0.5f), 0), NBX - 1);
    int ixh = min((int)(xmax * 0.5f) + 1, NBX);
    int iyl = min(max((int)(ymin * 0.5f), 0), NBY - 1);
    int iyh = min((int)(ymax * 0.5f) + 1, NBY);
    float w = net_weights[i];
    float inv_h = 1.0f / (ymax - ymin + TINY);
    float inv_v = 1.0f / (xmax - xmin + TINY);
    #pragma unroll
    for (int dx = 0; dx < MAX_SPAN; ++dx) {
        int bx = ixl + dx;
        if (bx >= ixh) break;
        float bxl = (float)bx * BSX;
        float ox = fmaxf(fminf(xmax, bxl + BSX) - fmaxf(xmin, bxl), 0.0f);
        float wox = w * ox;
        #pragma unroll
        for (int dy = 0; dy < MAX_SPAN; ++dy) {
            int by = iyl + dy;
            if (by >= iyh) break;
            float byl = (float)by * BSY;
            float oy = fmaxf(fminf(ymax, byl + BSY) - fmaxf(ymin, byl), 0.0f);
            float ov = wox * oy;
            float hq = ov * inv_h * FP_SCALE + 0.5f;
            float vq = ov * inv_v * FP_SCALE + 0.5f;
            ull packed = ((ull)(unsigned int)hq << 32) | (ull)(unsigned int)vq;
            atomicAdd(&hv[bx * NBY + by], packed);
        }
    }
}

__global__ void rudy_final_fb(const ull* __restrict__ hv,
                              float* __restrict__ out, int n)
{
    int k = blockIdx.x * blockDim.x + threadIdx.x;
    if (k >= n) return;
    const float scale = FP_INV * (1.0f / 6.0f);
    ull p = hv[k];
    float h = (float)(unsigned int)(p >> 32) * scale;
    float v = (float)(unsigned int)(p & 0xFFFFFFFFull) * scale;
    out[k] = fmaxf(h, v);
}

// ============================ launcher ============================

extern "C" void kernel_launch(void* const* d_in, const int* in_sizes, int n_in,
                              void* d_out, int out_size, void* d_ws, size_t ws_size,
                              hipStream_t stream)
{
    const float* pin_pos      = (const float*)d_in[0];
    const float* net_weights  = (const float*)d_in[1];
    const int*   netpin_start = (const int*)d_in[2];
    const int*   flat_netpin  = (const int*)d_in[3];

    int num_nets = in_sizes[1];
    int n_total  = in_sizes[0] / 2;

    // ws layout: [cursor 256KB][partial 16MB][list 25.2MB]
    size_t off_partial = (size_t)NTILES * G * CSTRIDE * sizeof(u32);                 // 256 KB
    size_t off_list    = off_partial + (size_t)NTILES * G * TS * TS * sizeof(ull);   // +16 MB
    size_t need        = off_list + (size_t)NTILES * G * SEG * sizeof(uint4);        // +25.2 MB

    if (ws_size >= need) {
        u32*   cursor  = (u32*)d_ws;
        ull*   partial = (ull*)((char*)d_ws + off_partial);
        uint4* list    = (uint4*)((char*)d_ws + off_list);

        init_cursors<<<(NTILES * G + 255) / 256, 256, 0, stream>>>(cursor);

        int nb = (num_nets + NPB - 1) / NPB;
        bin_nets<<<nb, BTH, 0, stream>>>(pin_pos, net_weights,
                                         netpin_start, flat_netpin,
                                         cursor, list,
                                         num_nets, n_total);

        accum_part<<<NTILES * G, ATH, 0, stream>>>(list, cursor, partial);

        merge_final<<<(NBX * NBY) / 256, 256, 0, stream>>>(partial, (float*)d_out);
    } else {
        // fallback: packed fixed-point global atomics
        ull* hv = (ull*)d_ws;
        hipMemsetAsync(hv, 0, (size_t)NBX * NBY * sizeof(ull), stream);
        int threads = 256;
        int blocks = (num_nets + threads - 1) / threads;
        rudy_accum_fb<<<blocks, threads, 0, stream>>>(pin_pos, net_weights,
                                                      netpin_start, flat_netpin,
                                                      hv, num_nets, n_total);
        int n = NBX * NBY;
        rudy_final_fb<<<(n + 255) / 256, 256, 0, stream>>>(hv, (float*)d_out, n);
    }
}

// Round 12
// 46.156 us; speedup vs baseline: 1.0384x; 1.0384x over previous
//
#include <hip/hip_runtime.h>
#include <float.h>

// Problem constants (match reference)
#define BSX 2.0f
#define BSY 2.0f
#define NBX 512
#define NBY 512
#define MAX_SPAN 4
#define TINY 1.17549435e-38f   // np.finfo(float32).tiny

// ---- Tiled path parameters ----
#define TSB 5                  // log2(tile size in bins): 32x32 bins = 64x64 units
#define TS  32
#define NTT 16                 // tiles per axis (512/32)
#define NTILES 256
#define BTH 256
#define NPT 4                  // nets per thread
#define NPB (BTH * NPT)        // nets per block = 1024
#define CSTRIDE 32             // cursor padding: 32 u32 = 128 B = one line per counter
#define G 8                    // cursor/list shards per tile
#define SEG 1024               // entries per (tile,shard) segment (mean ~537, +21 sigma)
#define ATH 1024               // accum threads: thread tid owns slot tid of each segment

// fixed-point accumulation scale (validated r2/r5: per-bin sums ~150 << 2^9 headroom)
#define FP_SCALE 4194304.0f    // 2^22
#define FP_INV   (1.0f / 4194304.0f)

typedef unsigned int u32;
typedef unsigned long long ull;

// Entry (16B, self-contained), tile-local quantized bbox + premultiplied weights:
//   x: x0q(1/1024 unit) | dxq(1/16384)<<16
//   y: y0q | dyq<<16
//   z: bits(w/(dy+tiny))   [h weight]
//   w: bits(w/(dx+tiny))   [v weight]

// ============================ tiled path ============================

// Minimal-phase binning: count -> reserve -> direct-scatter emit. (r11 structure)
__global__ __launch_bounds__(BTH) void bin_nets(
    const float* __restrict__ pin_pos,
    const float* __restrict__ net_weights,
    const int*   __restrict__ netpin_start,
    const int*   __restrict__ flat_netpin,
    u32*         __restrict__ cursor,     // [NTILES*G] padded by CSTRIDE
    uint4*       __restrict__ list,       // [NTILES*G][SEG]
    int num_nets, int n_total)
{
    __shared__ u32 s_cnt[NTILES];     // counts -> segment bases
    __shared__ u32 s_fill[NTILES];    // emit fill offsets

    int tid = threadIdx.x;
    int g = blockIdx.x & (G - 1);     // shard for this block
    s_cnt[tid] = 0u; s_fill[tid] = 0u;   // BTH == NTILES
    __syncthreads();

    int bs = blockIdx.x * NPB;

    // ---- phase-split loads: max memory-level parallelism ----
    int sA[NPT], eA[NPT];
    #pragma unroll
    for (int k = 0; k < NPT; ++k) {
        sA[k] = 0; eA[k] = 0;
        int i = bs + k * BTH + tid;
        if (i < num_nets) { sA[k] = netpin_start[i]; eA[k] = netpin_start[i + 1]; }
    }
    int4 fA[NPT];
    #pragma unroll
    for (int k = 0; k < NPT; ++k) {
        fA[k] = make_int4(-1, -1, -1, -1);
        if (eA[k] - sA[k] == 4 && (sA[k] & 3) == 0)
            fA[k] = *(const int4*)(flat_netpin + sA[k]);
    }
    bool idA[NPT];
    float4 xvA[NPT], yvA[NPT];
    #pragma unroll
    for (int k = 0; k < NPT; ++k) {
        int s = sA[k];
        idA[k] = (fA[k].x == s && fA[k].y == s + 1 && fA[k].z == s + 2 && fA[k].w == s + 3);
        if (idA[k]) {
            xvA[k] = *(const float4*)(pin_pos + s);
            yvA[k] = *(const float4*)(pin_pos + s + n_total);
        }
    }
    float wgt[NPT];
    #pragma unroll
    for (int k = 0; k < NPT; ++k) {
        int i = bs + k * BTH + tid;
        wgt[k] = (i < num_nets) ? net_weights[i] : 0.0f;
    }

    // ---- pass 1: bbox + per-tile counting ----
    float fx0[NPT], fx1[NPT], fy0[NPT], fy1[NPT], fwh[NPT], fwv[NPT];
    u32 trng[NPT];   // packed txl | txh<<8 | tyl<<16 | tyh<<24 ; 0x01 => invalid

    #pragma unroll
    for (int k = 0; k < NPT; ++k) {
        trng[k] = 0x00000001u;
        fx0[k] = 0.f; fx1[k] = 0.f; fy0[k] = 0.f; fy1[k] = 0.f;
        fwh[k] = 0.f; fwv[k] = 0.f;
        int i = bs + k * BTH + tid;
        if (i < num_nets) {
            bool have = false;
            float xmin, xmax, ymin, ymax;
            if (idA[k]) {
                xmin = fminf(fminf(xvA[k].x, xvA[k].y), fminf(xvA[k].z, xvA[k].w));
                xmax = fmaxf(fmaxf(xvA[k].x, xvA[k].y), fmaxf(xvA[k].z, xvA[k].w));
                ymin = fminf(fminf(yvA[k].x, yvA[k].y), fminf(yvA[k].z, yvA[k].w));
                ymax = fmaxf(fmaxf(yvA[k].x, yvA[k].y), fmaxf(yvA[k].z, yvA[k].w));
                have = true;
            } else if (eA[k] > sA[k]) {
                xmin = FLT_MAX; xmax = -FLT_MAX; ymin = FLT_MAX; ymax = -FLT_MAX;
                for (int p = sA[k]; p < eA[k]; ++p) {
                    int idx = flat_netpin[p];
                    float x = pin_pos[idx], y = pin_pos[idx + n_total];
                    xmin = fminf(xmin, x); xmax = fmaxf(xmax, x);
                    ymin = fminf(ymin, y); ymax = fmaxf(ymax, y);
                }
                have = true;
            }
            if (have) {
                fx0[k] = xmin; fx1[k] = xmax; fy0[k] = ymin; fy1[k] = ymax;
                fwh[k] = wgt[k] / (ymax - ymin + TINY);
                fwv[k] = wgt[k] / (xmax - xmin + TINY);
                int ixl = min(max((int)(xmin * 0.5f), 0), NBX - 1);
                int ixh = min(min((int)(xmax * 0.5f) + 1, NBX), ixl + MAX_SPAN);
                int iyl = min(max((int)(ymin * 0.5f), 0), NBY - 1);
                int iyh = min(min((int)(ymax * 0.5f) + 1, NBY), iyl + MAX_SPAN);
                int txl = ixl >> TSB, txh = (ixh - 1) >> TSB;
                int tyl = iyl >> TSB, tyh = (iyh - 1) >> TSB;
                trng[k] = (u32)txl | ((u32)txh << 8) | ((u32)tyl << 16) | ((u32)tyh << 24);
                for (int tx = txl; tx <= txh; ++tx)
                    for (int ty = tyl; ty <= tyh; ++ty)
                        atomicAdd(&s_cnt[tx * NTT + ty], 1u);
            }
        }
    }
    __syncthreads();

    // ---- sharded global reserve: one atomic per touched tile ----
    {
        u32 c = s_cnt[tid];              // BTH == NTILES
        u32 gbase = 0;
        if (c) gbase = atomicAdd(&cursor[((u32)tid * G + (u32)g) * CSTRIDE], c);
        s_cnt[tid] = gbase;              // s_cnt now holds base within (tile,g) segment
    }
    __syncthreads();

    // ---- pass 2: direct-scatter emit (block's slots are contiguous) ----
    #pragma unroll
    for (int k = 0; k < NPT; ++k) {
        u32 tr = trng[k];
        int txl = (int)(tr & 0xFFu), txh = (int)((tr >> 8) & 0xFFu);
        int tyl = (int)((tr >> 16) & 0xFFu), tyh = (int)(tr >> 24);
        for (int tx = txl; tx <= txh; ++tx) {
            float tox = (float)(tx << TSB) * BSX;
            float rx0 = fminf(fmaxf(fx0[k] - tox, 0.0f), 64.0f);
            float rx1 = fminf(fmaxf(fx1[k] - tox, 0.0f), 64.0f);
            u32 x0q = min((u32)(rx0 * 1024.0f + 0.5f), 65535u);
            u32 dxq = min((u32)((rx1 - rx0) * 16384.0f + 0.5f), 65535u);
            for (int ty = tyl; ty <= tyh; ++ty) {
                float toy = (float)(ty << TSB) * BSY;
                float ry0 = fminf(fmaxf(fy0[k] - toy, 0.0f), 64.0f);
                float ry1 = fminf(fmaxf(fy1[k] - toy, 0.0f), 64.0f);
                u32 y0q = min((u32)(ry0 * 1024.0f + 0.5f), 65535u);
                u32 dyq = min((u32)((ry1 - ry0) * 16384.0f + 0.5f), 65535u);
                int t = tx * NTT + ty;
                uint4 pk;
                pk.x = x0q | (dxq << 16);
                pk.y = y0q | (dyq << 16);
                pk.z = __float_as_uint(fwh[k]);
                pk.w = __float_as_uint(fwv[k]);
                u32 slot = atomicAdd(&s_fill[t], 1u);
                u32 pos = s_cnt[t] + slot;
                if (pos < (u32)SEG)
                    list[(((size_t)t * G + (size_t)g) << 10) + pos] = pk;
            }
        }
    }
}

// One block per tile: thread tid owns slot tid of each of the tile's G segments.
// 8 guarded prefetch loads (full MLP) -> LDS u64 tile -> direct out write.
__global__ __launch_bounds__(ATH) void accum_tile(
    const uint4* __restrict__ list,
    const u32*   __restrict__ cursor,    // padded
    float*       __restrict__ out)
{
    __shared__ ull shv[TS * TS];   // packed fixed-point: hi32 = h, lo32 = v

    int t = blockIdx.x;
    int tid = threadIdx.x;
    shv[tid] = 0ull;               // ATH == TS*TS
    __syncthreads();

    // per-segment valid counts (uniform loads, broadcast)
    u32 ng0 = min(cursor[((u32)t * G + 0) * CSTRIDE], (u32)SEG);
    u32 ng1 = min(cursor[((u32)t * G + 1) * CSTRIDE], (u32)SEG);
    u32 ng2 = min(cursor[((u32)t * G + 2) * CSTRIDE], (u32)SEG);
    u32 ng3 = min(cursor[((u32)t * G + 3) * CSTRIDE], (u32)SEG);
    u32 ng4 = min(cursor[((u32)t * G + 4) * CSTRIDE], (u32)SEG);
    u32 ng5 = min(cursor[((u32)t * G + 5) * CSTRIDE], (u32)SEG);
    u32 ng6 = min(cursor[((u32)t * G + 6) * CSTRIDE], (u32)SEG);
    u32 ng7 = min(cursor[((u32)t * G + 7) * CSTRIDE], (u32)SEG);

    const uint4* base = list + ((size_t)t * G << 10);

    // static 8-deep guarded prefetch: thread tid reads slot tid of each segment
    uint4 t0, t1, t2, t3, t4, t5, t6, t7;
    if ((u32)tid < ng0) t0 = base[(0 << 10) + tid];
    if ((u32)tid < ng1) t1 = base[(1 << 10) + tid];
    if ((u32)tid < ng2) t2 = base[(2 << 10) + tid];
    if ((u32)tid < ng3) t3 = base[(3 << 10) + tid];
    if ((u32)tid < ng4) t4 = base[(4 << 10) + tid];
    if ((u32)tid < ng5) t5 = base[(5 << 10) + tid];
    if ((u32)tid < ng6) t6 = base[(6 << 10) + tid];
    if ((u32)tid < ng7) t7 = base[(7 << 10) + tid];

    #define PROCESS(NG, PP)                                                     \
    if ((u32)tid < (NG)) {                                                      \
        uint4 p = (PP);                                                         \
        float x0 = (float)(p.x & 0xFFFFu) * (1.0f / 1024.0f);                   \
        float x1 = x0 + (float)(p.x >> 16) * (1.0f / 16384.0f);                 \
        float y0 = (float)(p.y & 0xFFFFu) * (1.0f / 1024.0f);                   \
        float y1 = y0 + (float)(p.y >> 16) * (1.0f / 16384.0f);                 \
        float wh = __uint_as_float(p.z);                                        \
        float wv = __uint_as_float(p.w);                                        \
        int rxl = min((int)(x0 * 0.5f), TS - 1);                                \
        int rxh = min((int)(x1 * 0.5f) + 1, TS);                                \
        int ryl = min((int)(y0 * 0.5f), TS - 1);                                \
        int ryh = min((int)(y1 * 0.5f) + 1, TS);                                \
        for (int bx = rxl; bx < rxh; ++bx) {                                    \
            float bl = (float)bx * BSX;                                         \
            float ox = fmaxf(fminf(x1, bl + BSX) - fmaxf(x0, bl), 0.0f);        \
            float oxh = ox * wh * FP_SCALE, oxv = ox * wv * FP_SCALE;           \
            int rowbase = bx * TS;                                              \
            for (int by = ryl; by < ryh; ++by) {                                \
                float bb = (float)by * BSY;                                     \
                float oy = fmaxf(fminf(y1, bb + BSY) - fmaxf(y0, bb), 0.0f);    \
                u32 hq = (u32)(oxh * oy + 0.5f);                                \
                u32 vq = (u32)(oxv * oy + 0.5f);                                \
                ull pk = ((ull)hq << 32) | (ull)vq;                             \
                atomicAdd(&shv[rowbase + by], pk);                              \
            }                                                                   \
        }                                                                       \
    }

    PROCESS(ng0, t0)  PROCESS(ng1, t1)  PROCESS(ng2, t2)  PROCESS(ng3, t3)
    PROCESS(ng4, t4)  PROCESS(ng5, t5)  PROCESS(ng6, t6)  PROCESS(ng7, t7)
    #undef PROCESS

    __syncthreads();

    // direct output write: tid = bx*32+by -> coalesced over by
    int tx = t >> 4, ty = t & 15;
    int bx = tid >> 5, by = tid & 31;
    ull p = shv[tid];
    float h = (float)(u32)(p >> 32);
    float v = (float)(u32)(p & 0xFFFFFFFFull);
    out[(size_t)(tx * TS + bx) * NBY + (ty * TS + by)] =
        fmaxf(h, v) * (FP_INV * (1.0f / 6.0f));
}

// ======================= fallback path (round-2) =======================

__global__ void rudy_accum_fb(const float* __restrict__ pin_pos,
                              const float* __restrict__ net_weights,
                              const int*   __restrict__ netpin_start,
                              const int*   __restrict__ flat_netpin,
                              ull*         __restrict__ hv,
                              int num_nets, int n_total)
{
    int i = blockIdx.x * blockDim.x + threadIdx.x;
    if (i >= num_nets) return;
    int s = netpin_start[i], e = netpin_start[i + 1];
    if (e <= s) return;
    float xmin = FLT_MAX, xmax = -FLT_MAX, ymin = FLT_MAX, ymax = -FLT_MAX;
    for (int p = s; p < e; ++p) {
        int idx = flat_netpin[p];
        float x = pin_pos[idx], y = pin_pos[idx + n_total];
        xmin = fminf(xmin, x); xmax = fmaxf(xmax, x);
        ymin = fminf(ymin, y); ymax = fmaxf(ymax, y);
    }
    int ixl = min(max((int)(xmin * 0.5f), 0), NBX - 1);
    int ixh = min((int)(xmax * 0.5f) + 1, NBX);
    int iyl = min(max((int)(ymin * 0.5f), 0), NBY - 1);
    int iyh = min((int)(ymax * 0.5f) + 1, NBY);
    float w = net_weights[i];
    float inv_h = 1.0f / (ymax - ymin + TINY);
    float inv_v = 1.0f / (xmax - xmin + TINY);
    #pragma unroll
    for (int dx = 0; dx < MAX_SPAN; ++dx) {
        int bx = ixl + dx;
        if (bx >= ixh) break;
        float bxl = (float)bx * BSX;
        float ox = fmaxf(fminf(xmax, bxl + BSX) - fmaxf(xmin, bxl), 0.0f);
        float wox = w * ox;
        #pragma unroll
        for (int dy = 0; dy < MAX_SPAN; ++dy) {
            int by = iyl + dy;
            if (by >= iyh) break;
            float byl = (float)by * BSY;
            float oy = fmaxf(fminf(ymax, byl + BSY) - fmaxf(ymin, byl), 0.0f);
            float ov = wox * oy;
            float hq = ov * inv_h * FP_SCALE + 0.5f;
            float vq = ov * inv_v * FP_SCALE + 0.5f;
            ull packed = ((ull)(unsigned int)hq << 32) | (ull)(unsigned int)vq;
            atomicAdd(&hv[bx * NBY + by], packed);
        }
    }
}

__global__ void rudy_final_fb(const ull* __restrict__ hv,
                              float* __restrict__ out, int n)
{
    int k = blockIdx.x * blockDim.x + threadIdx.x;
    if (k >= n) return;
    const float scale = FP_INV * (1.0f / 6.0f);
    ull p = hv[k];
    float h = (float)(unsigned int)(p >> 32) * scale;
    float v = (float)(unsigned int)(p & 0xFFFFFFFFull) * scale;
    out[k] = fmaxf(h, v);
}

// ============================ launcher ============================

extern "C" void kernel_launch(void* const* d_in, const int* in_sizes, int n_in,
                              void* d_out, int out_size, void* d_ws, size_t ws_size,
                              hipStream_t stream)
{
    const float* pin_pos      = (const float*)d_in[0];
    const float* net_weights  = (const float*)d_in[1];
    const int*   netpin_start = (const int*)d_in[2];
    const int*   flat_netpin  = (const int*)d_in[3];

    int num_nets = in_sizes[1];
    int n_total  = in_sizes[0] / 2;

    // ws layout: [cursor 256KB][list: NTILES*G*SEG*16B = 32MB]
    size_t off_list = (size_t)NTILES * G * CSTRIDE * sizeof(u32);                 // 256 KB
    size_t need     = off_list + ((size_t)NTILES * G * SEG) * sizeof(uint4);      // +32 MB

    if (ws_size >= need) {
        u32*   cursor = (u32*)d_ws;
        uint4* list   = (uint4*)((char*)d_ws + off_list);

        hipMemsetAsync(cursor, 0, off_list, stream);   // DMA fill, no kernel launch

        int nb = (num_nets + NPB - 1) / NPB;
        bin_nets<<<nb, BTH, 0, stream>>>(pin_pos, net_weights,
                                         netpin_start, flat_netpin,
                                         cursor, list,
                                         num_nets, n_total);

        accum_tile<<<NTILES, ATH, 0, stream>>>(list, cursor, (float*)d_out);
    } else {
        // fallback: packed fixed-point global atomics
        ull* hv = (ull*)d_ws;
        hipMemsetAsync(hv, 0, (size_t)NBX * NBY * sizeof(ull), stream);
        int threads = 256;
        int blocks = (num_nets + threads - 1) / threads;
        rudy_accum_fb<<<blocks, threads, 0, stream>>>(pin_pos, net_weights,
                                                      netpin_start, flat_netpin,
                                                      hv, num_nets, n_total);
        int n = NBX * NBY;
        rudy_final_fb<<<(n + 255) / 256, 256, 0, stream>>>(hv, (float*)d_out, n);
    }
}